// Round 3
// baseline (652.154 us; speedup 1.0000x reference)
//
#include <hip/hip_runtime.h>
#include <math.h>

#define NROWS 4096
#define DDIM  128
#define IMG_ELEMS 50331648LL   // 4096*3*64*64

typedef __attribute__((ext_vector_type(8))) short short8;   // 8 bf16 = 4 VGPRs
typedef __attribute__((ext_vector_type(4))) float floatx4;  // MFMA acc

// ws layout (bytes):
//   [0,40)   : 5 doubles [0]=mse [1]=kld [2]=Spp [3]=Szz [4]=Spz
//   [40,44)  : unsigned completion counter
//   [64,+16K): nP row norms (f32)   [then nZ]
//   then 4 x 1MB: Phi, Plo, Zhi, Zlo (bf16 as ushort, 4096x128 row-major)
#define WS_CNT  40
#define WS_NP   64
#define WS_NZ   (WS_NP + 16384)
#define WS_PHI  (WS_NZ + 16384)
#define WS_PLO  (WS_PHI + 1048576)
#define WS_ZHI  (WS_PLO + 1048576)
#define WS_ZLO  (WS_ZHI + 1048576)

// fused grid: period-29 interleave of roles for CU-level overlap
#define PERIOD     29
#define NGROUPS    160
#define NBLK_TOTAL (NGROUPS * PERIOD)   // 4640
#define NBLK_GRAM  2080                 // 528 pp + 528 zz + 1024 pz
#define NBLK_MSE   2080
#define NBLK_KLD   480

__device__ __forceinline__ unsigned short f2bf(float f) {
    unsigned u = __float_as_uint(f);
    return (unsigned short)((u + 0x7FFFu + ((u >> 16) & 1u)) >> 16);   // RNE
}
__device__ __forceinline__ float bf2f(unsigned short h) {
    return __uint_as_float(((unsigned)h) << 16);
}

__device__ __forceinline__ void async_ld16(const void* g, void* l) {
    __builtin_amdgcn_global_load_lds(
        (const __attribute__((address_space(1))) unsigned int*)g,
        (__attribute__((address_space(3))) unsigned int*)l, 16, 0, 0);
}

// ---------- prep: fp32 -> bf16 hi/lo planes + exact row norms + zero control ----------
// 2048 blocks x 256: block b handles 4 rows of (b<1024 ? P : Z), one wave per row.
__global__ __launch_bounds__(256) void prep_kernel(const float* __restrict__ P,
                                                   const float* __restrict__ Z,
                                                   char* __restrict__ wsb) {
    if (blockIdx.x == 0) {
        if (threadIdx.x < 5) ((double*)wsb)[threadIdx.x] = 0.0;
        if (threadIdx.x == 5) *(unsigned*)(wsb + WS_CNT) = 0u;
    }
    const int b = blockIdx.x;
    const int w = threadIdx.x >> 6, lane = threadIdx.x & 63;
    const int row = (b & 1023) * 4 + w;
    const float* src;
    unsigned short *hi, *lo;
    float* nrm;
    if (b < 1024) {
        src = P;
        hi = (unsigned short*)(wsb + WS_PHI); lo = (unsigned short*)(wsb + WS_PLO);
        nrm = (float*)(wsb + WS_NP);
    } else {
        src = Z;
        hi = (unsigned short*)(wsb + WS_ZHI); lo = (unsigned short*)(wsb + WS_ZLO);
        nrm = (float*)(wsb + WS_NZ);
    }
    float2 v = ((const float2*)(src + (size_t)row * DDIM))[lane];
    unsigned short hx = f2bf(v.x), hy = f2bf(v.y);
    unsigned short lx = f2bf(v.x - bf2f(hx)), ly = f2bf(v.y - bf2f(hy));
    ((ushort2*)(hi + (size_t)row * DDIM))[lane] = make_ushort2(hx, hy);
    ((ushort2*)(lo + (size_t)row * DDIM))[lane] = make_ushort2(lx, ly);
    float s = v.x * v.x + v.y * v.y;
    #pragma unroll
    for (int o = 32; o > 0; o >>= 1) s += __shfl_down(s, o);
    if (lane == 0) nrm[row] = s;
}

// ---------- fused: gram (MFMA) + mse (HBM) + kld, last block finalizes ----------
__global__ __launch_bounds__(256) void fused_kernel(char* __restrict__ wsb,
                                                    const float4* __restrict__ recons,
                                                    const float4* __restrict__ x,
                                                    const float4* __restrict__ mu,
                                                    const float4* __restrict__ lv,
                                                    float* __restrict__ out) {
    __shared__ __align__(16) unsigned short sA[128 * 32];
    __shared__ __align__(16) unsigned short sB[128 * 32];
    __shared__ double red[4];

    double* ws = (double*)wsb;
    const int grp = blockIdx.x / PERIOD;
    const int rrole = blockIdx.x % PERIOD;
    const int tid = threadIdx.x, lane = tid & 63, w = tid >> 6;

    if (rrole < 13) {
        // ===================== GRAM role =====================
        const int gi = grp * 13 + rrole;   // 0..2079
        int g, ti, tj;
        double wt = 1.0;
        if (gi < 1056) {
            g = (gi < 528) ? 0 : 1;
            const int t = (gi < 528) ? gi : gi - 528;
            int tjj = (int)((sqrt(8.0 * (double)t + 1.0) - 1.0) * 0.5);
            if ((tjj + 1) * (tjj + 2) / 2 <= t) tjj++;
            else if (tjj * (tjj + 1) / 2 > t) tjj--;
            ti = t - tjj * (tjj + 1) / 2;
            tj = tjj;
            wt = (ti == tj) ? 1.0 : 2.0;
        } else {
            g = 2;
            const int t = gi - 1056;
            ti = t >> 5; tj = t & 31;
        }

        const unsigned short* Phi = (const unsigned short*)(wsb + WS_PHI);
        const unsigned short* Plo = (const unsigned short*)(wsb + WS_PLO);
        const unsigned short* Zhi = (const unsigned short*)(wsb + WS_ZHI);
        const unsigned short* Zlo = (const unsigned short*)(wsb + WS_ZLO);
        const float* nP = (const float*)(wsb + WS_NP);
        const float* nZ = (const float*)(wsb + WS_NZ);
        const unsigned short *Ahi, *Alo, *Bhi, *Blo;
        const float *nI, *nJ;
        if (g == 0)      { Ahi = Phi; Alo = Plo; Bhi = Phi; Blo = Plo; nI = nP; nJ = nP; }
        else if (g == 1) { Ahi = Zhi; Alo = Zlo; Bhi = Zhi; Blo = Zlo; nI = nZ; nJ = nZ; }
        else             { Ahi = Phi; Alo = Plo; Bhi = Zhi; Blo = Zlo; nI = nP; nJ = nZ; }

        const int i0 = ti * 128, j0 = tj * 128;
        const int qi = (w >> 1) * 64, qj = (w & 1) * 64;
        const int fr = lane & 15, fq = lane >> 4;

        floatx4 acc[4][4];
        const floatx4 zero4 = {0.f, 0.f, 0.f, 0.f};
        #pragma unroll
        for (int a = 0; a < 4; a++)
            #pragma unroll
            for (int b = 0; b < 4; b++) acc[a][b] = zero4;

        #pragma unroll
        for (int pass = 0; pass < 3; pass++) {
            const unsigned short* As = (pass == 2) ? Alo : Ahi;  // hi,hi,lo
            const unsigned short* Bs = (pass == 1) ? Blo : Bhi;  // hi,lo,hi
            for (int kc = 0; kc < DDIM; kc += 32) {
                __syncthreads();
                #pragma unroll
                for (int t2 = 0; t2 < 2; t2++) {
                    const int r  = ((t2 * 4 + w) << 4) + (lane >> 2);
                    const int ko = (lane & 3) * 8;
                    async_ld16(As + (size_t)(i0 + r) * DDIM + kc + ko,
                               (char*)sA + r * 64 + ko * 2);
                    async_ld16(Bs + (size_t)(j0 + r) * DDIM + kc + ko,
                               (char*)sB + r * 64 + ko * 2);
                }
                __syncthreads();

                short8 af[4], bf[4];
                #pragma unroll
                for (int a = 0; a < 4; a++)
                    af[a] = *(const short8*)((const char*)sA + (qi + a * 16 + fr) * 64 + fq * 16);
                #pragma unroll
                for (int b = 0; b < 4; b++)
                    bf[b] = *(const short8*)((const char*)sB + (qj + b * 16 + fr) * 64 + fq * 16);
                #pragma unroll
                for (int a = 0; a < 4; a++)
                    #pragma unroll
                    for (int b = 0; b < 4; b++)
                        acc[a][b] = __builtin_amdgcn_mfma_f32_16x16x32_bf16(
                            af[a], bf[b], acc[a][b], 0, 0, 0);
            }
        }

        const float cc = 1.0f / 65536.0f;   // 1/(D * 2*D*z_var)
        float nj_[4];
        #pragma unroll
        for (int b = 0; b < 4; b++) nj_[b] = nJ[j0 + qj + b * 16 + fr];
        float sum = 0.f;
        #pragma unroll
        for (int a = 0; a < 4; a++) {
            #pragma unroll
            for (int r = 0; r < 4; r++) {
                const float ni = nI[i0 + qi + a * 16 + fq * 4 + r];
                #pragma unroll
                for (int b = 0; b < 4; b++)
                    sum += expf(cc * (2.f * acc[a][b][r] - ni - nj_[b]));
            }
        }

        double v = (double)sum;
        #pragma unroll
        for (int o = 32; o > 0; o >>= 1) v += __shfl_down(v, o);
        if (lane == 0) red[w] = v;
        __syncthreads();
        if (tid == 0) atomicAdd(&ws[2 + g], wt * (red[0] + red[1] + red[2] + red[3]));

    } else if (rrole < 26) {
        // ===================== MSE role =====================
        const int mb = grp * 13 + (rrole - 13);   // 0..2079
        const int half = (int)(IMG_ELEMS / 8);    // 6291456 float4s per stream
        const int stride = NBLK_MSE * 256;
        float acc = 0.f;
        for (int i = mb * 256 + tid; i < half; i += stride) {
            float4 a0 = recons[i],        b0 = x[i];
            float4 a1 = recons[i + half], b1 = x[i + half];
            float d;
            d = a0.x - b0.x; acc += d * d;  d = a0.y - b0.y; acc += d * d;
            d = a0.z - b0.z; acc += d * d;  d = a0.w - b0.w; acc += d * d;
            d = a1.x - b1.x; acc += d * d;  d = a1.y - b1.y; acc += d * d;
            d = a1.z - b1.z; acc += d * d;  d = a1.w - b1.w; acc += d * d;
        }
        double v = (double)acc;
        #pragma unroll
        for (int o = 32; o > 0; o >>= 1) v += __shfl_down(v, o);
        if (lane == 0) red[w] = v;
        __syncthreads();
        if (tid == 0) atomicAdd(&ws[0], red[0] + red[1] + red[2] + red[3]);

    } else {
        // ===================== KLD role =====================
        const int kb = grp * 3 + (rrole - 26);    // 0..479
        const int n4 = NROWS * DDIM / 4;          // 131072
        const int stride = NBLK_KLD * 256;
        float s = 0.f;
        for (int i = kb * 256 + tid; i < n4; i += stride) {
            float4 m = mu[i], l = lv[i];
            s += (1.f + l.x - m.x * m.x - expf(l.x))
               + (1.f + l.y - m.y * m.y - expf(l.y))
               + (1.f + l.z - m.z * m.z - expf(l.z))
               + (1.f + l.w - m.w * m.w - expf(l.w));
        }
        double v = (double)s;
        #pragma unroll
        for (int o = 32; o > 0; o >>= 1) v += __shfl_down(v, o);
        if (lane == 0) red[w] = v;
        __syncthreads();
        if (tid == 0) atomicAdd(&ws[1], red[0] + red[1] + red[2] + red[3]);
    }

    // ---------- completion counter; last block finalizes ----------
    if (tid == 0) {
        __threadfence();
        unsigned old = atomicAdd((unsigned*)(wsb + WS_CNT), 1u);
        if (old == NBLK_TOTAL - 1) {
            __threadfence();
            double s0 = atomicAdd(&ws[0], 0.0);
            double s1 = atomicAdd(&ws[1], 0.0);
            double s2 = atomicAdd(&ws[2], 0.0);
            double s3 = atomicAdd(&ws[3], 0.0);
            double s4 = atomicAdd(&ws[4], 0.0);
            const double Nd = (double)NROWS;
            double recons_loss = s0 / (double)IMG_ELEMS;
            double kld = -0.5 * s1 / Nd;
            double mmd = (s2 + s3 - 2.0 * s4) / (Nd * Nd);
            double bias_corr = Nd * (Nd - 1.0);
            double loss = 5.0 * recons_loss
                        + 1.5 * (1.0 / Nd) * kld
                        + (98.5 / bias_corr) * mmd;
            out[0] = (float)loss;
            out[1] = (float)recons_loss;
            out[2] = (float)mmd;
            out[3] = (float)(-kld);
        }
    }
}

extern "C" void kernel_launch(void* const* d_in, const int* in_sizes, int n_in,
                              void* d_out, int out_size, void* d_ws, size_t ws_size,
                              hipStream_t stream) {
    const float* recons  = (const float*)d_in[0];
    const float* x       = (const float*)d_in[1];
    const float* z       = (const float*)d_in[2];
    const float* mu      = (const float*)d_in[3];
    const float* log_var = (const float*)d_in[4];
    const float* prior_z = (const float*)d_in[5];
    char* wsb = (char*)d_ws;
    float* out = (float*)d_out;

    prep_kernel<<<2048, 256, 0, stream>>>(prior_z, z, wsb);
    fused_kernel<<<NBLK_TOTAL, 256, 0, stream>>>(wsb,
                                                 (const float4*)recons, (const float4*)x,
                                                 (const float4*)mu, (const float4*)log_var,
                                                 out);
}

// Round 4
// 535.970 us; speedup vs baseline: 1.2168x; 1.2168x over previous
//
#include <hip/hip_runtime.h>
#include <math.h>

#define NROWS 4096
#define DDIM  128
#define IMG_ELEMS 50331648LL   // 4096*3*64*64
#define N4F4   12582912        // IMG_ELEMS/4 (float4 count)
#define NBLK_GRAM 2080         // 528 pp + 528 zz + 1024 pz tiles (128x128)
#define MSTRIDE (NBLK_GRAM * 256)   // 532480 threads

typedef __attribute__((ext_vector_type(8))) short short8;   // 8 bf16 = 4 VGPRs
typedef __attribute__((ext_vector_type(4))) float floatx4;  // MFMA acc

// ws layout (bytes):
//   [0,40)   : 5 doubles [0]=mse [1]=kld [2]=Spp [3]=Szz [4]=Spz
//   [40,44)  : unsigned completion counter (zeroed by hipMemsetAsync)
//   [64,+16K): nP row norms (f32), then nZ
//   then 4 x 1MB: Phi, Plo, Zhi, Zlo (bf16 as ushort, 4096x128 row-major)
#define WS_CNT  40
#define WS_NP   64
#define WS_NZ   (WS_NP + 16384)
#define WS_PHI  (WS_NZ + 16384)
#define WS_PLO  (WS_PHI + 1048576)
#define WS_ZHI  (WS_PLO + 1048576)
#define WS_ZLO  (WS_ZHI + 1048576)

__device__ __forceinline__ unsigned short f2bf(float f) {
    unsigned u = __float_as_uint(f);
    return (unsigned short)((u + 0x7FFFu + ((u >> 16) & 1u)) >> 16);   // RNE
}
__device__ __forceinline__ float bf2f(unsigned short h) {
    return __uint_as_float(((unsigned)h) << 16);
}

__device__ __forceinline__ void async_ld16(const void* g, void* l) {
    __builtin_amdgcn_global_load_lds(
        (const __attribute__((address_space(1))) unsigned int*)g,
        (__attribute__((address_space(3))) unsigned int*)l, 16, 0, 0);
}

// safe for repeated use (trailing barrier)
__device__ __forceinline__ void block_reduce_atomic(double v, double wt,
                                                    double* dst, double* sm) {
    #pragma unroll
    for (int o = 32; o > 0; o >>= 1) v += __shfl_down(v, o);
    const int lane = threadIdx.x & 63, w = threadIdx.x >> 6;
    if (lane == 0) sm[w] = v;
    __syncthreads();
    if (threadIdx.x == 0) atomicAdd(dst, wt * (sm[0] + sm[1] + sm[2] + sm[3]));
    __syncthreads();
}

// ---------- prep: fp32 -> bf16 hi/lo planes + exact row norms + kld ----------
// 2048 blocks x 256. Block b: 4 rows (wave each) of (b<1024 ? P : Z); plus each
// thread handles one scalar element of the kld sum.
__global__ __launch_bounds__(256) void prep_kernel(const float* __restrict__ P,
                                                   const float* __restrict__ Z,
                                                   const float* __restrict__ mu,
                                                   const float* __restrict__ lv,
                                                   char* __restrict__ wsb) {
    __shared__ double sm[4];
    const int b = blockIdx.x;
    const int w = threadIdx.x >> 6, lane = threadIdx.x & 63;
    const int row = (b & 1023) * 4 + w;
    const float* src;
    unsigned short *hi, *lo;
    float* nrm;
    if (b < 1024) {
        src = P;
        hi = (unsigned short*)(wsb + WS_PHI); lo = (unsigned short*)(wsb + WS_PLO);
        nrm = (float*)(wsb + WS_NP);
    } else {
        src = Z;
        hi = (unsigned short*)(wsb + WS_ZHI); lo = (unsigned short*)(wsb + WS_ZLO);
        nrm = (float*)(wsb + WS_NZ);
    }
    float2 v = ((const float2*)(src + (size_t)row * DDIM))[lane];
    unsigned short hx = f2bf(v.x), hy = f2bf(v.y);
    unsigned short lx = f2bf(v.x - bf2f(hx)), ly = f2bf(v.y - bf2f(hy));
    ((ushort2*)(hi + (size_t)row * DDIM))[lane] = make_ushort2(hx, hy);
    ((ushort2*)(lo + (size_t)row * DDIM))[lane] = make_ushort2(lx, ly);
    float s = v.x * v.x + v.y * v.y;
    #pragma unroll
    for (int o = 32; o > 0; o >>= 1) s += __shfl_down(s, o);
    if (lane == 0) nrm[row] = s;

    // kld: one scalar element per thread (4096*128 = 2048*256 exactly)
    const int t = b * 256 + threadIdx.x;
    float m = mu[t], l = lv[t];
    float ks = 1.f + l - m * m - expf(l);
    block_reduce_atomic((double)ks, 1.0, &((double*)wsb)[1], sm);
}

// ---------- gram+mse fused: MFMA gram tiles with mse stream interleaved ----------
__global__ __launch_bounds__(256) void gram_mse_kernel(char* __restrict__ wsb,
                                                       const float4* __restrict__ recons,
                                                       const float4* __restrict__ x,
                                                       float* __restrict__ out) {
    __shared__ __align__(16) unsigned short sA[128 * 32];
    __shared__ __align__(16) unsigned short sB[128 * 32];
    __shared__ double sm[4];

    double* ws = (double*)wsb;
    const int tid = threadIdx.x, lane = tid & 63, w = tid >> 6;

    // ---- tile decode: 0..527 pp (tri), 528..1055 zz (tri), 1056.. pz (full) ----
    const int gi = blockIdx.x;
    int g, ti, tj;
    double wt = 1.0;
    if (gi < 1056) {
        g = (gi < 528) ? 0 : 1;
        const int t = (gi < 528) ? gi : gi - 528;
        int tjj = (int)((sqrt(8.0 * (double)t + 1.0) - 1.0) * 0.5);
        if ((tjj + 1) * (tjj + 2) / 2 <= t) tjj++;
        else if (tjj * (tjj + 1) / 2 > t) tjj--;
        ti = t - tjj * (tjj + 1) / 2;
        tj = tjj;
        wt = (ti == tj) ? 1.0 : 2.0;
    } else {
        g = 2;
        const int t = gi - 1056;
        ti = t >> 5; tj = t & 31;
    }

    const unsigned short* Phi = (const unsigned short*)(wsb + WS_PHI);
    const unsigned short* Plo = (const unsigned short*)(wsb + WS_PLO);
    const unsigned short* Zhi = (const unsigned short*)(wsb + WS_ZHI);
    const unsigned short* Zlo = (const unsigned short*)(wsb + WS_ZLO);
    const float* nP = (const float*)(wsb + WS_NP);
    const float* nZ = (const float*)(wsb + WS_NZ);
    const unsigned short *Ahi, *Alo, *Bhi, *Blo;
    const float *nI, *nJ;
    if (g == 0)      { Ahi = Phi; Alo = Plo; Bhi = Phi; Blo = Plo; nI = nP; nJ = nP; }
    else if (g == 1) { Ahi = Zhi; Alo = Zlo; Bhi = Zhi; Blo = Zlo; nI = nZ; nJ = nZ; }
    else             { Ahi = Phi; Alo = Plo; Bhi = Zhi; Blo = Zlo; nI = nP; nJ = nZ; }

    const int i0 = ti * 128, j0 = tj * 128;
    const int qi = (w >> 1) * 64, qj = (w & 1) * 64;
    const int fr = lane & 15, fq = lane >> 4;

    floatx4 acc[4][4];
    const floatx4 zero4 = {0.f, 0.f, 0.f, 0.f};
    #pragma unroll
    for (int a = 0; a < 4; a++)
        #pragma unroll
        for (int b = 0; b < 4; b++) acc[a][b] = zero4;

    const int mse_base = gi * 256 + tid;   // 0..532479
    float mse_acc = 0.f;

    // 12 K-chunks: pass = c>>2 (hi*hi, hi*lo, lo*hi), kc = (c&3)*32
    #pragma unroll 1
    for (int c = 0; c < 12; c++) {
        const int pass = c >> 2, kc = (c & 3) << 5;
        const unsigned short* As = (pass == 2) ? Alo : Ahi;  // hi,hi,lo
        const unsigned short* Bs = (pass == 1) ? Blo : Bhi;  // hi,lo,hi

        __syncthreads();   // previous chunk's LDS readers done
        #pragma unroll
        for (int t2 = 0; t2 < 2; t2++) {
            const int r  = ((t2 * 4 + w) << 4) + (lane >> 2);
            const int ko = (lane & 3) * 8;
            async_ld16(As + (size_t)(i0 + r) * DDIM + kc + ko,
                       (char*)sA + r * 64 + ko * 2);
            async_ld16(Bs + (size_t)(j0 + r) * DDIM + kc + ko,
                       (char*)sB + r * 64 + ko * 2);
        }

        // mse stream: 2 float4-pairs per thread per chunk, issued so their
        // latency overlaps the staging drain + this chunk's MFMA
        const int i1 = mse_base + (2 * c) * MSTRIDE;
        const int i2 = i1 + MSTRIDE;
        float4 a0 = recons[i1], b0 = x[i1];
        float4 a1, b1;
        const bool ok2 = (i2 < N4F4);
        if (ok2) { a1 = recons[i2]; b1 = x[i2]; }

        __syncthreads();   // staging (and mse loads) drained

        short8 af[4], bf[4];
        #pragma unroll
        for (int a = 0; a < 4; a++)
            af[a] = *(const short8*)((const char*)sA + (qi + a * 16 + fr) * 64 + fq * 16);
        #pragma unroll
        for (int b = 0; b < 4; b++)
            bf[b] = *(const short8*)((const char*)sB + (qj + b * 16 + fr) * 64 + fq * 16);
        #pragma unroll
        for (int a = 0; a < 4; a++)
            #pragma unroll
            for (int b = 0; b < 4; b++)
                acc[a][b] = __builtin_amdgcn_mfma_f32_16x16x32_bf16(
                    af[a], bf[b], acc[a][b], 0, 0, 0);

        float d;
        d = a0.x - b0.x; mse_acc += d * d;  d = a0.y - b0.y; mse_acc += d * d;
        d = a0.z - b0.z; mse_acc += d * d;  d = a0.w - b0.w; mse_acc += d * d;
        if (ok2) {
            d = a1.x - b1.x; mse_acc += d * d;  d = a1.y - b1.y; mse_acc += d * d;
            d = a1.z - b1.z; mse_acc += d * d;  d = a1.w - b1.w; mse_acc += d * d;
        }
    }
    __syncthreads();

    // gram epilogue: k_ij = exp(cc*(2*dot - ni - nj)), cc = 1/(D * 2*D*z_var)
    const float cc = 1.0f / 65536.0f;
    float nj_[4];
    #pragma unroll
    for (int b = 0; b < 4; b++) nj_[b] = nJ[j0 + qj + b * 16 + fr];
    float sum = 0.f;
    #pragma unroll
    for (int a = 0; a < 4; a++) {
        #pragma unroll
        for (int r = 0; r < 4; r++) {
            const float ni = nI[i0 + qi + a * 16 + fq * 4 + r];
            #pragma unroll
            for (int b = 0; b < 4; b++)
                sum += expf(cc * (2.f * acc[a][b][r] - ni - nj_[b]));
        }
    }

    block_reduce_atomic((double)sum, wt, &ws[2 + g], sm);
    block_reduce_atomic((double)mse_acc, 1.0, &ws[0], sm);

    // ---------- completion counter; last block finalizes ----------
    if (tid == 0) {
        __threadfence();
        unsigned old = atomicAdd((unsigned*)(wsb + WS_CNT), 1u);
        if (old == NBLK_GRAM - 1) {
            __threadfence();
            double s0 = atomicAdd(&ws[0], 0.0);
            double s1 = atomicAdd(&ws[1], 0.0);
            double s2 = atomicAdd(&ws[2], 0.0);
            double s3 = atomicAdd(&ws[3], 0.0);
            double s4 = atomicAdd(&ws[4], 0.0);
            const double Nd = (double)NROWS;
            double recons_loss = s0 / (double)IMG_ELEMS;
            double kld = -0.5 * s1 / Nd;
            double mmd = (s2 + s3 - 2.0 * s4) / (Nd * Nd);
            double bias_corr = Nd * (Nd - 1.0);
            double loss = 5.0 * recons_loss
                        + 1.5 * (1.0 / Nd) * kld
                        + (98.5 / bias_corr) * mmd;
            out[0] = (float)loss;
            out[1] = (float)recons_loss;
            out[2] = (float)mmd;
            out[3] = (float)(-kld);
        }
    }
}

extern "C" void kernel_launch(void* const* d_in, const int* in_sizes, int n_in,
                              void* d_out, int out_size, void* d_ws, size_t ws_size,
                              hipStream_t stream) {
    const float* recons  = (const float*)d_in[0];
    const float* x       = (const float*)d_in[1];
    const float* z       = (const float*)d_in[2];
    const float* mu      = (const float*)d_in[3];
    const float* log_var = (const float*)d_in[4];
    const float* prior_z = (const float*)d_in[5];
    char* wsb = (char*)d_ws;
    float* out = (float*)d_out;

    hipMemsetAsync(d_ws, 0, 48, stream);   // 5 doubles + counter
    prep_kernel<<<2048, 256, 0, stream>>>(prior_z, z, mu, log_var, wsb);
    gram_mse_kernel<<<NBLK_GRAM, 256, 0, stream>>>(wsb,
                                                   (const float4*)recons,
                                                   (const float4*)x, out);
}